// Round 2
// baseline (301.882 us; speedup 1.0000x reference)
//
#include <hip/hip_runtime.h>

// ---------------- bf16 helpers (raw ushort storage; RNE convert) ----------------
typedef unsigned short ushort_t;
typedef unsigned int uint_t;

__device__ __forceinline__ float bf2f(ushort_t u) {
    union { float f; uint_t i; } c; c.i = ((uint_t)u) << 16; return c.f;
}
__device__ __forceinline__ ushort_t f2bf(float f) {
    union { float f; uint_t i; } c; c.f = f;
    uint_t i = c.i;
    uint_t r = (i + 0x7fffu + ((i >> 16) & 1u)) >> 16;   // round-nearest-even
    return (ushort_t)r;
}

typedef __attribute__((ext_vector_type(8))) short short8;
typedef __attribute__((ext_vector_type(4))) float float4v;

// ---------------- problem constants ----------------
#define BATCH 16384
#define NF    26
#define NV    100000
#define ED    16
#define NCONT 13
#define H     400
// K1 layout: [0..415] emb bf16 | [416..431] cont_hi | [432..447] cont_lo | [448..463] cont_hi | [464..479] zero
// W1t layout:[0..415] W1emb    | [416..431] w_hi    | [432..447] w_hi    | [448..463] w_lo    | [464..479] zero
// => MFMA computes emb@W + ch*wh + cl*wh + ch*wl  (cont side near-exact)
#define K1    480
#define K2    416   // h1[0..399] + 16 zero pad

// ws offsets (bytes), all 16-aligned
#define OFF_DNN   0u
#define OFF_A2    15728640u   // 16384*480*2
#define OFF_W1T   29360128u   // +16384*416*2
#define OFF_W2T   29744128u   // +400*480*2
#define OFF_FM    30076928u   // +400*416*2
#define OFF_OACC  30142464u   // +16384*4
// end: 30208000 (~28.8 MB)

// ================= K0: cast + pad + transpose weights =================
__global__ void prep_weights(const float* __restrict__ W1,
                             const float* __restrict__ W2,
                             ushort_t* __restrict__ W1t,
                             ushort_t* __restrict__ W2t) {
    int i = blockIdx.x * 256 + threadIdx.x;
    if (i < H * K1) {
        int n = i / K1, k = i % K1;
        ushort_t o = 0;
        if (k < 416) {
            o = f2bf(W1[(size_t)(13 + k) * H + n]);          // emb rows of W1
        } else if (k < 448) {
            int j = k - (k < 432 ? 416 : 432);
            if (j < NCONT) o = f2bf(W1[(size_t)j * H + n]);  // w_hi (twice)
        } else if (k < 464) {
            int j = k - 448;
            if (j < NCONT) {
                float w = W1[(size_t)j * H + n];
                ushort_t wh = f2bf(w);
                o = f2bf(w - bf2f(wh));                      // w_lo
            }
        }
        W1t[i] = o;
    } else {
        int j = i - H * K1;
        if (j < H * K2) {
            int n = j / K2, k = j % K2;
            W2t[j] = (k < 400) ? f2bf(W2[(size_t)k * H + n]) : (ushort_t)0;
        }
    }
}

// ================= K1: gather + FM (fp32 exact) + build dnn plane =================
// one wave per batch row; 4 waves/block
__global__ __launch_bounds__(256) void gather_fm(
    const float* __restrict__ cont, const int* __restrict__ cat,
    const float* __restrict__ w_cont, const float* __restrict__ b_cont,
    const float* __restrict__ t_first, const float* __restrict__ t_emb,
    ushort_t* __restrict__ dnn, ushort_t* __restrict__ A2,
    float* __restrict__ fm_out) {
    int tid  = threadIdx.x;
    int lane = tid & 63;
    int b    = blockIdx.x * 4 + (tid >> 6);

    int idxv = (lane < NF) ? cat[b * NF + lane] : 0;

    // continuous: fp32 first-order dot + hi/lo bf16 split into dnn
    float p = 0.f;
    if (lane < NCONT) {
        float c = cont[b * NCONT + lane];
        ushort_t ch = f2bf(c);
        float cl = c - bf2f(ch);
        dnn[(size_t)b * K1 + 416 + lane] = ch;
        dnn[(size_t)b * K1 + 432 + lane] = f2bf(cl);
        dnn[(size_t)b * K1 + 448 + lane] = ch;
        p = c * w_cont[lane];
    } else if (lane < 16) {
        dnn[(size_t)b * K1 + 416 + lane] = 0;
        dnn[(size_t)b * K1 + 432 + lane] = 0;
        dnn[(size_t)b * K1 + 448 + lane] = 0;
    }
    if (lane < 16) dnn[(size_t)b * K1 + 464 + lane] = 0;
    if (lane < NF) p += t_first[(size_t)lane * NV + idxv];
    #pragma unroll
    for (int off = 1; off < 64; off <<= 1) p += __shfl_xor(p, off);

    // embeddings: 4 fields per iteration, lane = fsub*16 + e; fp32 FM2 accum
    int e = lane & 15, fsub = lane >> 4;
    float s = 0.f, ss = 0.f;
    for (int it = 0; it < 7; ++it) {
        int f = it * 4 + fsub;
        if (f < NF) {
            int idxf = __shfl(idxv, f);
            float v = t_emb[((size_t)(f * NV + idxf)) * ED + e];
            dnn[(size_t)b * K1 + f * ED + e] = f2bf(v);
            s += v; ss += v * v;
        }
    }
    s  += __shfl_xor(s, 16);  s  += __shfl_xor(s, 32);
    ss += __shfl_xor(ss, 16); ss += __shfl_xor(ss, 32);
    float u = s * s - ss;
    u += __shfl_xor(u, 1); u += __shfl_xor(u, 2);
    u += __shfl_xor(u, 4); u += __shfl_xor(u, 8);

    if (lane == 0) fm_out[b] = p + b_cont[0] + 0.5f * u;

    // zero A2 pad cols 400..415
    if (lane < 16) A2[(size_t)b * K2 + 400 + lane] = 0;
}

// ================= K2: GEMM1 (dnn @ W1t^T) + bias + relu -> A2 bf16 =================
// 256 thr = 4 waves; tile 128(M) x 80(N); wave = 32 rows x 80 cols
__global__ __launch_bounds__(256) void gemm1_k(
    const ushort_t* __restrict__ A, const ushort_t* __restrict__ Bt,
    const float* __restrict__ bias, ushort_t* __restrict__ A2) {
    __shared__ __align__(16) ushort_t lsa[128 * 40];
    __shared__ __align__(16) ushort_t lsb[80 * 40];
    int tid  = threadIdx.x;
    int m0   = (blockIdx.x / 5) * 128;
    int n0   = (blockIdx.x % 5) * 80;
    int wave = tid >> 6, lane = tid & 63;
    int quad = lane >> 4, mrow = lane & 15;

    float4v acc[2][5] = {};

    for (int k0 = 0; k0 < K1; k0 += 32) {
        __syncthreads();
        #pragma unroll
        for (int c = tid; c < 512; c += 256) {
            int r = c >> 2, sgm = c & 3;
            *(uint4*)(&lsa[r * 40 + sgm * 8]) =
                *(const uint4*)(&A[(size_t)(m0 + r) * K1 + k0 + sgm * 8]);
        }
        for (int c = tid; c < 320; c += 256) {
            int r = c >> 2, sgm = c & 3;
            *(uint4*)(&lsb[r * 40 + sgm * 8]) =
                *(const uint4*)(&Bt[(size_t)(n0 + r) * K1 + k0 + sgm * 8]);
        }
        __syncthreads();
        short8 af0 = *(const short8*)(&lsa[(wave * 32 + mrow) * 40 + quad * 8]);
        short8 af1 = *(const short8*)(&lsa[(wave * 32 + 16 + mrow) * 40 + quad * 8]);
        #pragma unroll
        for (int ni = 0; ni < 5; ++ni) {
            short8 bfr = *(const short8*)(&lsb[(ni * 16 + mrow) * 40 + quad * 8]);
            acc[0][ni] = __builtin_amdgcn_mfma_f32_16x16x32_bf16(af0, bfr, acc[0][ni], 0, 0, 0);
            acc[1][ni] = __builtin_amdgcn_mfma_f32_16x16x32_bf16(af1, bfr, acc[1][ni], 0, 0, 0);
        }
    }

    #pragma unroll
    for (int mi = 0; mi < 2; ++mi)
        #pragma unroll
        for (int ni = 0; ni < 5; ++ni) {
            int col = n0 + ni * 16 + mrow;
            float bv = bias[col];
            #pragma unroll
            for (int reg = 0; reg < 4; ++reg) {
                int row = m0 + wave * 32 + mi * 16 + quad * 4 + reg;
                float h = fmaxf(acc[mi][ni][reg] + bv, 0.f);
                A2[(size_t)row * K2 + col] = f2bf(h);
            }
        }
}

// ================= K3: GEMM2 (A2 @ W2t^T) + bias + relu + W_out partial dot =================
__global__ __launch_bounds__(256) void gemm2_k(
    const ushort_t* __restrict__ A, const ushort_t* __restrict__ Bt,
    const float* __restrict__ bias, const float* __restrict__ Wout,
    float* __restrict__ oacc) {
    __shared__ __align__(16) ushort_t lsa[128 * 40];
    __shared__ __align__(16) ushort_t lsb[80 * 40];
    int tid  = threadIdx.x;
    int m0   = (blockIdx.x / 5) * 128;
    int n0   = (blockIdx.x % 5) * 80;
    int wave = tid >> 6, lane = tid & 63;
    int quad = lane >> 4, mrow = lane & 15;

    float4v acc[2][5] = {};

    for (int k0 = 0; k0 < K2; k0 += 32) {
        __syncthreads();
        #pragma unroll
        for (int c = tid; c < 512; c += 256) {
            int r = c >> 2, sgm = c & 3;
            *(uint4*)(&lsa[r * 40 + sgm * 8]) =
                *(const uint4*)(&A[(size_t)(m0 + r) * K2 + k0 + sgm * 8]);
        }
        for (int c = tid; c < 320; c += 256) {
            int r = c >> 2, sgm = c & 3;
            *(uint4*)(&lsb[r * 40 + sgm * 8]) =
                *(const uint4*)(&Bt[(size_t)(n0 + r) * K2 + k0 + sgm * 8]);
        }
        __syncthreads();
        short8 af0 = *(const short8*)(&lsa[(wave * 32 + mrow) * 40 + quad * 8]);
        short8 af1 = *(const short8*)(&lsa[(wave * 32 + 16 + mrow) * 40 + quad * 8]);
        #pragma unroll
        for (int ni = 0; ni < 5; ++ni) {
            short8 bfr = *(const short8*)(&lsb[(ni * 16 + mrow) * 40 + quad * 8]);
            acc[0][ni] = __builtin_amdgcn_mfma_f32_16x16x32_bf16(af0, bfr, acc[0][ni], 0, 0, 0);
            acc[1][ni] = __builtin_amdgcn_mfma_f32_16x16x32_bf16(af1, bfr, acc[1][ni], 0, 0, 0);
        }
    }

    float p0[4] = {0.f, 0.f, 0.f, 0.f};
    float p1[4] = {0.f, 0.f, 0.f, 0.f};
    #pragma unroll
    for (int ni = 0; ni < 5; ++ni) {
        int col = n0 + ni * 16 + mrow;
        float bv = bias[col];
        float wv = Wout[1 + col];
        #pragma unroll
        for (int reg = 0; reg < 4; ++reg) {
            p0[reg] += fmaxf(acc[0][ni][reg] + bv, 0.f) * wv;
            p1[reg] += fmaxf(acc[1][ni][reg] + bv, 0.f) * wv;
        }
    }
    #pragma unroll
    for (int reg = 0; reg < 4; ++reg) {
        #pragma unroll
        for (int off = 1; off < 16; off <<= 1) {
            p0[reg] += __shfl_xor(p0[reg], off);
            p1[reg] += __shfl_xor(p1[reg], off);
        }
    }
    if (mrow == 0) {
        int rbase = m0 + wave * 32 + quad * 4;
        #pragma unroll
        for (int reg = 0; reg < 4; ++reg) {
            atomicAdd(&oacc[rbase + reg],      p0[reg]);
            atomicAdd(&oacc[rbase + 16 + reg], p1[reg]);
        }
    }
}

// ================= K4: finalize (fp32 out) =================
__global__ void finalize_k(const float* __restrict__ oacc,
                           const float* __restrict__ fm_out,
                           const float* __restrict__ Wout,
                           const float* __restrict__ bout,
                           float* __restrict__ out) {
    int i = blockIdx.x * 256 + threadIdx.x;
    out[i] = oacc[i] + fm_out[i] * Wout[0] + bout[0];
}

// ================= launch =================
extern "C" void kernel_launch(void* const* d_in, const int* in_sizes, int n_in,
                              void* d_out, int out_size, void* d_ws, size_t ws_size,
                              hipStream_t stream) {
    const float* cont    = (const float*)d_in[0];
    const int*   cat     = (const int*)d_in[1];
    const float* w_cont  = (const float*)d_in[2];
    const float* b_cont  = (const float*)d_in[3];
    const float* t_first = (const float*)d_in[4];
    const float* t_emb   = (const float*)d_in[5];
    const float* W1      = (const float*)d_in[6];
    const float* b1      = (const float*)d_in[7];
    const float* W2      = (const float*)d_in[8];
    const float* b2      = (const float*)d_in[9];
    const float* Wout    = (const float*)d_in[10];
    const float* bout    = (const float*)d_in[11];
    float* out = (float*)d_out;

    char* w = (char*)d_ws;
    ushort_t* dnn  = (ushort_t*)(w + OFF_DNN);
    ushort_t* A2   = (ushort_t*)(w + OFF_A2);
    ushort_t* W1t  = (ushort_t*)(w + OFF_W1T);
    ushort_t* W2t  = (ushort_t*)(w + OFF_W2T);
    float*    fm   = (float*)(w + OFF_FM);
    float*    oacc = (float*)(w + OFF_OACC);

    // K0: weight prep (400*480 + 400*416 = 358400 elems = 1400 * 256)
    prep_weights<<<1400, 256, 0, stream>>>(W1, W2, W1t, W2t);
    // K1: gather + FM + dnn build
    gather_fm<<<BATCH / 4, 256, 0, stream>>>(cont, cat, w_cont, b_cont,
                                             t_first, t_emb, dnn, A2, fm);
    // zero output accumulator (ws is poisoned 0xAA before every call)
    hipMemsetAsync(oacc, 0, BATCH * sizeof(float), stream);
    // K2: GEMM1
    gemm1_k<<<(BATCH / 128) * 5, 256, 0, stream>>>(dnn, W1t, b1, A2);
    // K3: GEMM2 + fused output dot
    gemm2_k<<<(BATCH / 128) * 5, 256, 0, stream>>>(A2, W2t, b2, Wout, oacc);
    // K4: finalize
    finalize_k<<<BATCH / 256, 256, 0, stream>>>(oacc, fm, Wout, bout, out);
}

// Round 3
// 284.778 us; speedup vs baseline: 1.0601x; 1.0601x over previous
//
#include <hip/hip_runtime.h>

// ---------------- bf16 helpers (raw ushort storage; RNE convert) ----------------
typedef unsigned short ushort_t;
typedef unsigned int uint_t;

__device__ __forceinline__ float bf2f(ushort_t u) {
    union { float f; uint_t i; } c; c.i = ((uint_t)u) << 16; return c.f;
}
__device__ __forceinline__ ushort_t f2bf(float f) {
    union { float f; uint_t i; } c; c.f = f;
    uint_t i = c.i;
    return (ushort_t)((i + 0x7fffu + ((i >> 16) & 1u)) >> 16);   // RNE
}

typedef __attribute__((ext_vector_type(8))) short short8;
typedef __attribute__((ext_vector_type(4))) float float4v;

// ---------------- problem constants ----------------
#define BATCH 16384
#define NV    100000
#define NPAD  448     // H=400 padded to 28 tiles of 16 (zero weight rows)
#define K1    480     // [0..415] emb | [416..431] c_hi | [432..447] c_lo | [448..463] c_hi | [464..479] 0
#define K2    416     // h1 400 + 16 zero
#define SA    488     // smA row stride (elems); 976 B = 61*16, bank starts r*20%32 -> 2-way (free)
#define SH    456     // smH row stride; 912 B, starts r*4%32 -> 2-way (free)

#define OFF_W1T 0u           // 448*480*2 = 430080 B
#define OFF_W2T 430080u      // 448*416*2 = 372736 B   (total ~803 KB of ws)

// ================= K0: cast + pad + transpose weights =================
// W1t[n][k] (448 x 480) with cont hi/lo trick; W2t[n][k] (448 x 416). Rows n>=400 zero.
__global__ void prep_weights(const float* __restrict__ W1, const float* __restrict__ W2,
                             ushort_t* __restrict__ W1t, ushort_t* __restrict__ W2t) {
    int i = blockIdx.x * 256 + threadIdx.x;
    if (i < NPAD * K1) {
        int n = i / K1, k = i % K1;
        ushort_t o = 0;
        if (n < 400) {
            if (k < 416) {
                o = f2bf(W1[(size_t)(13 + k) * 400 + n]);            // emb rows
            } else if (k < 448) {
                int j = k - (k < 432 ? 416 : 432);
                if (j < 13) o = f2bf(W1[(size_t)j * 400 + n]);       // w_hi (twice)
            } else if (k < 464) {
                int j = k - 448;
                if (j < 13) {
                    float wv = W1[(size_t)j * 400 + n];
                    ushort_t wh = f2bf(wv);
                    o = f2bf(wv - bf2f(wh));                         // w_lo
                }
            }
        }
        W1t[i] = o;
    } else {
        int j = i - NPAD * K1;
        if (j < NPAD * K2) {
            int n = j / K2, k = j % K2;
            W2t[j] = (n < 400 && k < 400) ? f2bf(W2[(size_t)k * 400 + n]) : (ushort_t)0;
        }
    }
}

// ================= K1: fully fused DeepFM =================
// 256 blocks x 256 threads; block owns 64 batch rows, everything LDS-resident.
__global__ __launch_bounds__(256, 2) void fused_deepfm(
    const float* __restrict__ cont, const int* __restrict__ cat,
    const float* __restrict__ w_cont, const float* __restrict__ b_cont,
    const float* __restrict__ t_first, const float* __restrict__ t_emb,
    const ushort_t* __restrict__ W1t, const float* __restrict__ b1,
    const ushort_t* __restrict__ W2t, const float* __restrict__ b2,
    const float* __restrict__ Wout, const float* __restrict__ bout,
    float* __restrict__ out)
{
    __shared__ __align__(16) ushort_t smA[64 * SA];   // 62464 B; aliased by smH (stride SH)
    __shared__ float smFM[64];
    __shared__ float smP[256];

    int tid  = threadIdx.x;
    int wv   = tid >> 6, lane = tid & 63;
    int quad = lane >> 4, mrow = lane & 15;
    int b0   = blockIdx.x * 64;
    ushort_t* smH = smA;

    // ---- Phase A: gather + FM (fp32 exact) + build dnn tile in LDS ----
    {
        int r4 = lane >> 4, fs = (lane >> 2) & 3, sub = lane & 3, l16 = lane & 15;
        for (int g = 0; g < 4; ++g) {
            int R  = wv * 16 + g * 4 + r4;
            int gR = b0 + R;
            float sj0 = 0, sj1 = 0, sj2 = 0, sj3 = 0, ssq = 0, pacc = 0;
            #pragma unroll
            for (int it = 0; it < 7; ++it) {
                int f = it * 4 + fs;
                if (f < 26) {
                    int idx = cat[gR * 26 + f];
                    const float* ep = t_emb + (((size_t)f * NV + idx) << 4) + sub * 4;
                    float4 v = *(const float4*)ep;
                    sj0 += v.x; sj1 += v.y; sj2 += v.z; sj3 += v.w;
                    ssq += v.x * v.x + v.y * v.y + v.z * v.z + v.w * v.w;
                    uint_t lo = (uint_t)f2bf(v.x) | ((uint_t)f2bf(v.y) << 16);
                    uint_t hi = (uint_t)f2bf(v.z) | ((uint_t)f2bf(v.w) << 16);
                    uint2 pk = make_uint2(lo, hi);
                    *(uint2*)&smA[R * SA + f * 16 + sub * 4] = pk;   // 8B-aligned
                    if (sub == 0) pacc += t_first[(size_t)f * NV + idx];
                }
            }
            // continuous: hi/lo split into cols 416..479 + fp32 first-order dot
            float c = (l16 < 13) ? cont[gR * 13 + l16] : 0.f;
            if (l16 < 13) pacc += c * w_cont[l16];
            ushort_t ch = f2bf(c);
            float cl = c - bf2f(ch);
            smA[R * SA + 416 + l16] = ch;
            smA[R * SA + 432 + l16] = f2bf(cl);
            smA[R * SA + 448 + l16] = ch;
            smA[R * SA + 464 + l16] = 0;
            // FM: sj over fs (xor 4,8), then 16-lane total
            sj0 += __shfl_xor(sj0, 4); sj0 += __shfl_xor(sj0, 8);
            sj1 += __shfl_xor(sj1, 4); sj1 += __shfl_xor(sj1, 8);
            sj2 += __shfl_xor(sj2, 4); sj2 += __shfl_xor(sj2, 8);
            sj3 += __shfl_xor(sj3, 4); sj3 += __shfl_xor(sj3, 8);
            float q = pacc - 0.5f * ssq;
            if (fs == 0) q += 0.5f * (sj0 * sj0 + sj1 * sj1 + sj2 * sj2 + sj3 * sj3);
            q += __shfl_xor(q, 1); q += __shfl_xor(q, 2);
            q += __shfl_xor(q, 4); q += __shfl_xor(q, 8);
            if (l16 == 0) smFM[R] = q + b_cont[0];
        }
    }
    __syncthreads();

    int n0 = wv * 7;   // this wave's n-tile base (28 tiles split 7/7/7/7)

    // ---- Phase B: GEMM1, B-frags streamed L2->regs (prefetch 1 slice), A from LDS ----
    {
        const ushort_t* Bb = W1t + (size_t)mrow * K1 + quad * 8;
        short8 bcur[7], bnxt[7];
        #pragma unroll
        for (int ni = 0; ni < 7; ++ni)
            bcur[ni] = *(const short8*)(Bb + (size_t)(n0 + ni) * 16 * K1);
        float4v acc[4][7] = {};
        #pragma unroll 1
        for (int s = 0; s < 15; ++s) {
            if (s < 14) {
                #pragma unroll
                for (int ni = 0; ni < 7; ++ni)
                    bnxt[ni] = *(const short8*)(Bb + (size_t)(n0 + ni) * 16 * K1 + (s + 1) * 32);
            }
            short8 af[4];
            #pragma unroll
            for (int mt = 0; mt < 4; ++mt)
                af[mt] = *(const short8*)&smA[(mt * 16 + mrow) * SA + s * 32 + quad * 8];
            #pragma unroll
            for (int ni = 0; ni < 7; ++ni)
                #pragma unroll
                for (int mt = 0; mt < 4; ++mt)
                    acc[mt][ni] = __builtin_amdgcn_mfma_f32_16x16x32_bf16(af[mt], bcur[ni], acc[mt][ni], 0, 0, 0);
            #pragma unroll
            for (int ni = 0; ni < 7; ++ni) bcur[ni] = bnxt[ni];
        }
        __syncthreads();   // all smA frag reads drained before smH overwrites the region
        #pragma unroll
        for (int ni = 0; ni < 7; ++ni) {
            int col = n0 * 16 + ni * 16 + mrow;
            float bv = (col < 400) ? b1[col] : 0.f;   // cols>=400: acc==0, bias 0 -> h=0
            #pragma unroll
            for (int mt = 0; mt < 4; ++mt)
                #pragma unroll
                for (int r = 0; r < 4; ++r) {
                    int row = mt * 16 + quad * 4 + r;
                    smH[row * SH + col] = f2bf(fmaxf(acc[mt][ni][r] + bv, 0.f));
                }
        }
    }
    __syncthreads();

    // ---- Phase C: GEMM2 + fused W_out dot ----
    {
        const ushort_t* Bb = W2t + (size_t)mrow * K2 + quad * 8;
        short8 bcur[7], bnxt[7];
        #pragma unroll
        for (int ni = 0; ni < 7; ++ni)
            bcur[ni] = *(const short8*)(Bb + (size_t)(n0 + ni) * 16 * K2);
        float4v acc[4][7] = {};
        #pragma unroll 1
        for (int s = 0; s < 13; ++s) {
            if (s < 12) {
                #pragma unroll
                for (int ni = 0; ni < 7; ++ni)
                    bnxt[ni] = *(const short8*)(Bb + (size_t)(n0 + ni) * 16 * K2 + (s + 1) * 32);
            }
            short8 af[4];
            #pragma unroll
            for (int mt = 0; mt < 4; ++mt)
                af[mt] = *(const short8*)&smH[(mt * 16 + mrow) * SH + s * 32 + quad * 8];
            #pragma unroll
            for (int ni = 0; ni < 7; ++ni)
                #pragma unroll
                for (int mt = 0; mt < 4; ++mt)
                    acc[mt][ni] = __builtin_amdgcn_mfma_f32_16x16x32_bf16(af[mt], bcur[ni], acc[mt][ni], 0, 0, 0);
            #pragma unroll
            for (int ni = 0; ni < 7; ++ni) bcur[ni] = bnxt[ni];
        }
        float p[4][4] = {};
        #pragma unroll
        for (int ni = 0; ni < 7; ++ni) {
            int col = n0 * 16 + ni * 16 + mrow;
            if (col < 400) {
                float bv = b2[col], wvv = Wout[1 + col];
                #pragma unroll
                for (int mt = 0; mt < 4; ++mt)
                    #pragma unroll
                    for (int r = 0; r < 4; ++r)
                        p[mt][r] += fmaxf(acc[mt][ni][r] + bv, 0.f) * wvv;
            }
        }
        #pragma unroll
        for (int mt = 0; mt < 4; ++mt)
            #pragma unroll
            for (int r = 0; r < 4; ++r) {
                float v = p[mt][r];
                v += __shfl_xor(v, 1); v += __shfl_xor(v, 2);
                v += __shfl_xor(v, 4); v += __shfl_xor(v, 8);
                p[mt][r] = v;
            }
        if (mrow == 0) {
            #pragma unroll
            for (int mt = 0; mt < 4; ++mt)
                #pragma unroll
                for (int r = 0; r < 4; ++r)
                    smP[wv * 64 + mt * 16 + quad * 4 + r] = p[mt][r];
        }
    }
    __syncthreads();

    // ---- finalize: combine 4 wave-partials + FM branch ----
    if (tid < 64) {
        float o = smP[tid] + smP[64 + tid] + smP[128 + tid] + smP[192 + tid];
        out[b0 + tid] = o + smFM[tid] * Wout[0] + bout[0];
    }
}

// ================= launch =================
extern "C" void kernel_launch(void* const* d_in, const int* in_sizes, int n_in,
                              void* d_out, int out_size, void* d_ws, size_t ws_size,
                              hipStream_t stream) {
    const float* cont    = (const float*)d_in[0];
    const int*   cat     = (const int*)d_in[1];
    const float* w_cont  = (const float*)d_in[2];
    const float* b_cont  = (const float*)d_in[3];
    const float* t_first = (const float*)d_in[4];
    const float* t_emb   = (const float*)d_in[5];
    const float* W1      = (const float*)d_in[6];
    const float* b1      = (const float*)d_in[7];
    const float* W2      = (const float*)d_in[8];
    const float* b2      = (const float*)d_in[9];
    const float* Wout    = (const float*)d_in[10];
    const float* bout    = (const float*)d_in[11];
    float* out = (float*)d_out;

    char* w = (char*)d_ws;
    ushort_t* W1t = (ushort_t*)(w + OFF_W1T);
    ushort_t* W2t = (ushort_t*)(w + OFF_W2T);

    // K0: weight prep (448*480 + 448*416 = 401408 elems = 1568 * 256)
    prep_weights<<<1568, 256, 0, stream>>>(W1, W2, W1t, W2t);
    // K1: fully fused forward
    fused_deepfm<<<BATCH / 64, 256, 0, stream>>>(cont, cat, w_cont, b_cont,
                                                 t_first, t_emb, W1t, b1, W2t, b2,
                                                 Wout, bout, out);
}

// Round 4
// 275.723 us; speedup vs baseline: 1.0949x; 1.0328x over previous
//
#include <hip/hip_runtime.h>

// ---------------- bf16 helpers (raw ushort storage; RNE convert) ----------------
typedef unsigned short ushort_t;
typedef unsigned int uint_t;

__device__ __forceinline__ float bf2f(ushort_t u) {
    union { float f; uint_t i; } c; c.i = ((uint_t)u) << 16; return c.f;
}
__device__ __forceinline__ ushort_t f2bf(float f) {
    union { float f; uint_t i; } c; c.f = f;
    uint_t i = c.i;
    return (ushort_t)((i + 0x7fffu + ((i >> 16) & 1u)) >> 16);   // RNE
}

typedef __attribute__((ext_vector_type(8))) short short8;
typedef __attribute__((ext_vector_type(4))) float float4v;

// ---------------- problem constants ----------------
#define BATCH 16384
#define NV    100000
#define NPAD  448     // H=400 padded to 28 tiles of 16 (zero weight rows)
#define K1    480     // [0..415] emb | [416..431] c_hi | [432..447] c_lo | [448..463] c_hi | [464..479] 0
#define K2    416     // h1 400 + 16 zero
#define ROWS  32      // batch rows per block (2 blocks/CU for phase overlap)
#define SA    488     // smA row stride (elems); 976 B -> 20-bank row skew -> 2-way (free)
#define SH    456     // smH row stride; 912 B -> 2-way (free)

#define OFF_W1T 0u           // 448*480*2 = 430080 B
#define OFF_W2T 430080u      // 448*416*2 = 372736 B   (total ~803 KB of ws)

// ================= K0: cast + pad + transpose weights =================
// W1t[n][k] (448 x 480) with cont hi/lo trick; W2t[n][k] (448 x 416). Rows n>=400 zero.
__global__ void prep_weights(const float* __restrict__ W1, const float* __restrict__ W2,
                             ushort_t* __restrict__ W1t, ushort_t* __restrict__ W2t) {
    int i = blockIdx.x * 256 + threadIdx.x;
    if (i < NPAD * K1) {
        int n = i / K1, k = i % K1;
        ushort_t o = 0;
        if (n < 400) {
            if (k < 416) {
                o = f2bf(W1[(size_t)(13 + k) * 400 + n]);            // emb rows
            } else if (k < 448) {
                int j = k - (k < 432 ? 416 : 432);
                if (j < 13) o = f2bf(W1[(size_t)j * 400 + n]);       // w_hi (twice)
            } else if (k < 464) {
                int j = k - 448;
                if (j < 13) {
                    float wv = W1[(size_t)j * 400 + n];
                    ushort_t wh = f2bf(wv);
                    o = f2bf(wv - bf2f(wh));                         // w_lo
                }
            }
        }
        W1t[i] = o;
    } else {
        int j = i - NPAD * K1;
        if (j < NPAD * K2) {
            int n = j / K2, k = j % K2;
            W2t[j] = (n < 400 && k < 400) ? f2bf(W2[(size_t)k * 400 + n]) : (ushort_t)0;
        }
    }
}

// ================= K1: fully fused DeepFM =================
// 512 blocks x 256 threads; block owns 32 batch rows; 2 blocks/CU so one block's
// gather overlaps the other's GEMM phases. Everything LDS-resident.
__global__ __launch_bounds__(256, 2) void fused_deepfm(
    const float* __restrict__ cont, const int* __restrict__ cat,
    const float* __restrict__ w_cont, const float* __restrict__ b_cont,
    const float* __restrict__ t_first, const float* __restrict__ t_emb,
    const ushort_t* __restrict__ W1t, const float* __restrict__ b1,
    const ushort_t* __restrict__ W2t, const float* __restrict__ b2,
    const float* __restrict__ Wout, const float* __restrict__ bout,
    float* __restrict__ out)
{
    __shared__ __align__(16) ushort_t smA[ROWS * SA];   // 31232 B; aliased by smH (stride SH)
    __shared__ float smFM[ROWS];
    __shared__ float smP[4 * ROWS];

    int tid  = threadIdx.x;
    int wv   = tid >> 6, lane = tid & 63;
    int quad = lane >> 4, mrow = lane & 15;
    int b0   = blockIdx.x * ROWS;
    ushort_t* smH = smA;

    // ---- Phase A: gather + FM (fp32 exact) + build dnn tile in LDS ----
    {
        int r4 = lane >> 4, fs = (lane >> 2) & 3, sub = lane & 3, l16 = lane & 15;
        // hoist all categorical index loads (max MLP before the dependent gathers)
        int idxv[2][7];
        #pragma unroll
        for (int g = 0; g < 2; ++g) {
            int gR = b0 + wv * 8 + g * 4 + r4;
            #pragma unroll
            for (int it = 0; it < 7; ++it) {
                int f = it * 4 + fs;
                idxv[g][it] = (f < 26) ? cat[gR * 26 + f] : 0;
            }
        }
        #pragma unroll
        for (int g = 0; g < 2; ++g) {
            int R  = wv * 8 + g * 4 + r4;
            int gR = b0 + R;
            float sj0 = 0, sj1 = 0, sj2 = 0, sj3 = 0, ssq = 0, pacc = 0;
            #pragma unroll
            for (int it = 0; it < 7; ++it) {
                int f = it * 4 + fs;
                if (f < 26) {
                    int idx = idxv[g][it];
                    const float* ep = t_emb + (((size_t)f * NV + idx) << 4) + sub * 4;
                    float4 v = *(const float4*)ep;
                    sj0 += v.x; sj1 += v.y; sj2 += v.z; sj3 += v.w;
                    ssq += v.x * v.x + v.y * v.y + v.z * v.z + v.w * v.w;
                    uint_t lo = (uint_t)f2bf(v.x) | ((uint_t)f2bf(v.y) << 16);
                    uint_t hi = (uint_t)f2bf(v.z) | ((uint_t)f2bf(v.w) << 16);
                    uint2 pk = make_uint2(lo, hi);
                    *(uint2*)&smA[R * SA + f * 16 + sub * 4] = pk;   // 8B-aligned
                    if (sub == 0) pacc += t_first[(size_t)f * NV + idx];
                }
            }
            // continuous: hi/lo split into cols 416..479 + fp32 first-order dot
            float c = (l16 < 13) ? cont[gR * 13 + l16] : 0.f;
            if (l16 < 13) pacc += c * w_cont[l16];
            ushort_t ch = f2bf(c);
            float cl = c - bf2f(ch);
            smA[R * SA + 416 + l16] = ch;
            smA[R * SA + 432 + l16] = f2bf(cl);
            smA[R * SA + 448 + l16] = ch;
            smA[R * SA + 464 + l16] = 0;
            // FM: sj over fs (xor 4,8), then 16-lane total
            sj0 += __shfl_xor(sj0, 4); sj0 += __shfl_xor(sj0, 8);
            sj1 += __shfl_xor(sj1, 4); sj1 += __shfl_xor(sj1, 8);
            sj2 += __shfl_xor(sj2, 4); sj2 += __shfl_xor(sj2, 8);
            sj3 += __shfl_xor(sj3, 4); sj3 += __shfl_xor(sj3, 8);
            float q = pacc - 0.5f * ssq;
            if (fs == 0) q += 0.5f * (sj0 * sj0 + sj1 * sj1 + sj2 * sj2 + sj3 * sj3);
            q += __shfl_xor(q, 1); q += __shfl_xor(q, 2);
            q += __shfl_xor(q, 4); q += __shfl_xor(q, 8);
            if (l16 == 0) smFM[R] = q + b_cont[0];
        }
    }
    __syncthreads();

    int n0 = wv * 7;   // this wave's n-tile base (28 tiles split 7/7/7/7)

    // ---- Phase B: GEMM1, B-frags streamed L2->regs (prefetch 1 slice), A from LDS ----
    {
        const ushort_t* Bb = W1t + (size_t)mrow * K1 + quad * 8;
        short8 bcur[7], bnxt[7];
        #pragma unroll
        for (int ni = 0; ni < 7; ++ni)
            bcur[ni] = *(const short8*)(Bb + (size_t)(n0 + ni) * 16 * K1);
        float4v acc[2][7] = {};
        #pragma unroll 1
        for (int s = 0; s < 15; ++s) {
            if (s < 14) {
                #pragma unroll
                for (int ni = 0; ni < 7; ++ni)
                    bnxt[ni] = *(const short8*)(Bb + (size_t)(n0 + ni) * 16 * K1 + (s + 1) * 32);
            }
            short8 af[2];
            #pragma unroll
            for (int mt = 0; mt < 2; ++mt)
                af[mt] = *(const short8*)&smA[(mt * 16 + mrow) * SA + s * 32 + quad * 8];
            #pragma unroll
            for (int ni = 0; ni < 7; ++ni)
                #pragma unroll
                for (int mt = 0; mt < 2; ++mt)
                    acc[mt][ni] = __builtin_amdgcn_mfma_f32_16x16x32_bf16(af[mt], bcur[ni], acc[mt][ni], 0, 0, 0);
            #pragma unroll
            for (int ni = 0; ni < 7; ++ni) bcur[ni] = bnxt[ni];
        }
        __syncthreads();   // all smA frag reads drained before smH overwrites the region
        #pragma unroll
        for (int ni = 0; ni < 7; ++ni) {
            int col = n0 * 16 + ni * 16 + mrow;
            float bv = (col < 400) ? b1[col] : 0.f;   // cols>=400: acc==0, bias 0 -> h=0
            #pragma unroll
            for (int mt = 0; mt < 2; ++mt)
                #pragma unroll
                for (int r = 0; r < 4; ++r) {
                    int row = mt * 16 + quad * 4 + r;
                    smH[row * SH + col] = f2bf(fmaxf(acc[mt][ni][r] + bv, 0.f));
                }
        }
    }
    __syncthreads();

    // ---- Phase C: GEMM2 + fused W_out dot ----
    {
        const ushort_t* Bb = W2t + (size_t)mrow * K2 + quad * 8;
        short8 bcur[7], bnxt[7];
        #pragma unroll
        for (int ni = 0; ni < 7; ++ni)
            bcur[ni] = *(const short8*)(Bb + (size_t)(n0 + ni) * 16 * K2);
        float4v acc[2][7] = {};
        #pragma unroll 1
        for (int s = 0; s < 13; ++s) {
            if (s < 12) {
                #pragma unroll
                for (int ni = 0; ni < 7; ++ni)
                    bnxt[ni] = *(const short8*)(Bb + (size_t)(n0 + ni) * 16 * K2 + (s + 1) * 32);
            }
            short8 af[2];
            #pragma unroll
            for (int mt = 0; mt < 2; ++mt)
                af[mt] = *(const short8*)&smH[(mt * 16 + mrow) * SH + s * 32 + quad * 8];
            #pragma unroll
            for (int ni = 0; ni < 7; ++ni)
                #pragma unroll
                for (int mt = 0; mt < 2; ++mt)
                    acc[mt][ni] = __builtin_amdgcn_mfma_f32_16x16x32_bf16(af[mt], bcur[ni], acc[mt][ni], 0, 0, 0);
            #pragma unroll
            for (int ni = 0; ni < 7; ++ni) bcur[ni] = bnxt[ni];
        }
        float p[2][4] = {};
        #pragma unroll
        for (int ni = 0; ni < 7; ++ni) {
            int col = n0 * 16 + ni * 16 + mrow;
            if (col < 400) {
                float bv = b2[col], wvv = Wout[1 + col];
                #pragma unroll
                for (int mt = 0; mt < 2; ++mt)
                    #pragma unroll
                    for (int r = 0; r < 4; ++r)
                        p[mt][r] += fmaxf(acc[mt][ni][r] + bv, 0.f) * wvv;
            }
        }
        #pragma unroll
        for (int mt = 0; mt < 2; ++mt)
            #pragma unroll
            for (int r = 0; r < 4; ++r) {
                float v = p[mt][r];
                v += __shfl_xor(v, 1); v += __shfl_xor(v, 2);
                v += __shfl_xor(v, 4); v += __shfl_xor(v, 8);
                p[mt][r] = v;
            }
        if (mrow == 0) {
            #pragma unroll
            for (int mt = 0; mt < 2; ++mt)
                #pragma unroll
                for (int r = 0; r < 4; ++r)
                    smP[wv * ROWS + mt * 16 + quad * 4 + r] = p[mt][r];
        }
    }
    __syncthreads();

    // ---- finalize: combine 4 wave-partials + FM branch ----
    if (tid < ROWS) {
        float o = smP[tid] + smP[ROWS + tid] + smP[2 * ROWS + tid] + smP[3 * ROWS + tid];
        out[b0 + tid] = o + smFM[tid] * Wout[0] + bout[0];
    }
}

// ================= launch =================
extern "C" void kernel_launch(void* const* d_in, const int* in_sizes, int n_in,
                              void* d_out, int out_size, void* d_ws, size_t ws_size,
                              hipStream_t stream) {
    const float* cont    = (const float*)d_in[0];
    const int*   cat     = (const int*)d_in[1];
    const float* w_cont  = (const float*)d_in[2];
    const float* b_cont  = (const float*)d_in[3];
    const float* t_first = (const float*)d_in[4];
    const float* t_emb   = (const float*)d_in[5];
    const float* W1      = (const float*)d_in[6];
    const float* b1      = (const float*)d_in[7];
    const float* W2      = (const float*)d_in[8];
    const float* b2      = (const float*)d_in[9];
    const float* Wout    = (const float*)d_in[10];
    const float* bout    = (const float*)d_in[11];
    float* out = (float*)d_out;

    char* w = (char*)d_ws;
    ushort_t* W1t = (ushort_t*)(w + OFF_W1T);
    ushort_t* W2t = (ushort_t*)(w + OFF_W2T);

    // K0: weight prep (448*480 + 448*416 = 401408 elems = 1568 * 256)
    prep_weights<<<1568, 256, 0, stream>>>(W1, W2, W1t, W2t);
    // K1: fully fused forward, 2 blocks/CU
    fused_deepfm<<<BATCH / ROWS, 256, 0, stream>>>(cont, cat, w_cont, b_cont,
                                                   t_first, t_emb, W1t, b1, W2t, b2,
                                                   Wout, bout, out);
}

// Round 5
// 265.938 us; speedup vs baseline: 1.1352x; 1.0368x over previous
//
#include <hip/hip_runtime.h>

// ---------------- bf16 helpers (raw ushort storage; RNE convert) ----------------
typedef unsigned short ushort_t;
typedef unsigned int uint_t;

__device__ __forceinline__ float bf2f(ushort_t u) {
    union { float f; uint_t i; } c; c.i = ((uint_t)u) << 16; return c.f;
}
__device__ __forceinline__ ushort_t f2bf(float f) {
    union { float f; uint_t i; } c; c.f = f;
    uint_t i = c.i;
    return (ushort_t)((i + 0x7fffu + ((i >> 16) & 1u)) >> 16);   // RNE
}

typedef __attribute__((ext_vector_type(8))) short short8;
typedef __attribute__((ext_vector_type(4))) float float4v;

// ---------------- problem constants ----------------
#define BATCH 16384
#define NV    100000
#define K1    480     // [0..415] emb | [416..431] c_hi | [432..447] c_lo | [448..463] c_hi | [464..479] 0
#define K2    416     // h1 400 + 16 zero pad
#define NT    25      // real n-tiles (400/16); ragged wave split 7/7/7/4
#define S1    15      // K1/32
#define S2    13      // K2/32
#define ROWS  32      // batch rows per block (2 blocks/CU for phase overlap)
#define SA    488     // smA row stride (elems); 976 B -> row skew -> <=2-way (free)
#define SH    456     // smH row stride; 912 B -> <=2-way (free)

// fragment-ordered weights: frag(t,s) = 64 lanes x 16B contiguous (1 KB)
#define OFF_W1F 0u           // 25*15*512*2 = 384000 B
#define OFF_W2F 384000u      // 25*13*512*2 = 332800 B  (total ~700 KB ws)

// ================= K0: cast + hi/lo split + repack to fragment order =================
__global__ void prep_weights(const float* __restrict__ W1, const float* __restrict__ W2,
                             ushort_t* __restrict__ W1f, ushort_t* __restrict__ W2f) {
    int i = blockIdx.x * 256 + threadIdx.x;
    if (i < 400 * K1) {
        int n = i / K1, k = i % K1;
        ushort_t o = 0;
        if (k < 416) {
            o = f2bf(W1[(size_t)(13 + k) * 400 + n]);            // emb rows
        } else if (k < 448) {
            int j = k - (k < 432 ? 416 : 432);
            if (j < 13) o = f2bf(W1[(size_t)j * 400 + n]);       // w_hi (twice)
        } else if (k < 464) {
            int j = k - 448;
            if (j < 13) {
                float wv = W1[(size_t)j * 400 + n];
                o = f2bf(wv - bf2f(f2bf(wv)));                   // w_lo
            }
        }
        int t = n >> 4, mr = n & 15, s = k >> 5, q = (k >> 3) & 3, j = k & 7;
        W1f[(size_t)((t * S1 + s) * 64 + q * 16 + mr) * 8 + j] = o;
    } else {
        int i2 = i - 400 * K1;
        if (i2 < 400 * K2) {
            int n = i2 / K2, k = i2 % K2;
            ushort_t o = (k < 400) ? f2bf(W2[(size_t)k * 400 + n]) : (ushort_t)0;
            int t = n >> 4, mr = n & 15, s = k >> 5, q = (k >> 3) & 3, j = k & 7;
            W2f[(size_t)((t * S2 + s) * 64 + q * 16 + mr) * 8 + j] = o;
        }
    }
}

// ================= K1: fully fused DeepFM =================
// 512 blocks x 256 threads; block owns 32 batch rows; 2 blocks/CU overlap phases.
__global__ __launch_bounds__(256, 2) void fused_deepfm(
    const float* __restrict__ cont, const int* __restrict__ cat,
    const float* __restrict__ w_cont, const float* __restrict__ b_cont,
    const float* __restrict__ t_first, const float* __restrict__ t_emb,
    const ushort_t* __restrict__ W1f, const float* __restrict__ b1,
    const ushort_t* __restrict__ W2f, const float* __restrict__ b2,
    const float* __restrict__ Wout, const float* __restrict__ bout,
    float* __restrict__ out)
{
    __shared__ __align__(16) ushort_t smA[ROWS * SA];   // 31232 B; aliased by smH (stride SH)
    __shared__ float smFM[ROWS];
    __shared__ float smP[4 * ROWS];

    int tid  = threadIdx.x;
    int wv   = tid >> 6, lane = tid & 63;
    int quad = lane >> 4, mrow = lane & 15;
    int b0   = blockIdx.x * ROWS;
    ushort_t* smH = smA;
    const int ntiles = (wv < 3) ? 7 : 4;   // ragged 7/7/7/4 over 25 real tiles

    // ---- Phase A: gather + FM (fp32 exact) + build dnn tile in LDS ----
    {
        int r4 = lane >> 4, fs = (lane >> 2) & 3, sub = lane & 3, l16 = lane & 15;
        int idxv[2][7];
        #pragma unroll
        for (int g = 0; g < 2; ++g) {
            int gR = b0 + wv * 8 + g * 4 + r4;
            #pragma unroll
            for (int it = 0; it < 7; ++it) {
                int f = it * 4 + fs;
                idxv[g][it] = (f < 26) ? cat[gR * 26 + f] : 0;
            }
        }
        #pragma unroll
        for (int g = 0; g < 2; ++g) {
            int R  = wv * 8 + g * 4 + r4;
            int gR = b0 + R;
            float sj0 = 0, sj1 = 0, sj2 = 0, sj3 = 0, ssq = 0, pacc = 0;
            #pragma unroll
            for (int it = 0; it < 7; ++it) {
                int f = it * 4 + fs;
                if (f < 26) {
                    int idx = idxv[g][it];
                    const float* ep = t_emb + (((size_t)f * NV + idx) << 4) + sub * 4;
                    float4 v = *(const float4*)ep;
                    sj0 += v.x; sj1 += v.y; sj2 += v.z; sj3 += v.w;
                    ssq += v.x * v.x + v.y * v.y + v.z * v.z + v.w * v.w;
                    uint_t lo = (uint_t)f2bf(v.x) | ((uint_t)f2bf(v.y) << 16);
                    uint_t hi = (uint_t)f2bf(v.z) | ((uint_t)f2bf(v.w) << 16);
                    uint2 pk = make_uint2(lo, hi);
                    *(uint2*)&smA[R * SA + f * 16 + sub * 4] = pk;   // 8B-aligned
                    if (sub == 0) pacc += t_first[(size_t)f * NV + idx];
                }
            }
            float c = (l16 < 13) ? cont[gR * 13 + l16] : 0.f;
            if (l16 < 13) pacc += c * w_cont[l16];
            ushort_t ch = f2bf(c);
            float cl = c - bf2f(ch);
            smA[R * SA + 416 + l16] = ch;
            smA[R * SA + 432 + l16] = f2bf(cl);
            smA[R * SA + 448 + l16] = ch;
            smA[R * SA + 464 + l16] = 0;
            sj0 += __shfl_xor(sj0, 4); sj0 += __shfl_xor(sj0, 8);
            sj1 += __shfl_xor(sj1, 4); sj1 += __shfl_xor(sj1, 8);
            sj2 += __shfl_xor(sj2, 4); sj2 += __shfl_xor(sj2, 8);
            sj3 += __shfl_xor(sj3, 4); sj3 += __shfl_xor(sj3, 8);
            float q = pacc - 0.5f * ssq;
            if (fs == 0) q += 0.5f * (sj0 * sj0 + sj1 * sj1 + sj2 * sj2 + sj3 * sj3);
            q += __shfl_xor(q, 1); q += __shfl_xor(q, 2);
            q += __shfl_xor(q, 4); q += __shfl_xor(q, 8);
            if (l16 == 0) smFM[R] = q + b_cont[0];
        }
    }
    __syncthreads();

    // ---- Phase B: GEMM1, fragment-ordered B streamed L2->regs, A from LDS ----
    {
        const ushort_t* Bb = W1f + (size_t)(wv * 7 * S1) * 512 + lane * 8;
        short8 bcur[7], bnxt[7];
        #pragma unroll
        for (int ni = 0; ni < 7; ++ni)
            if (ni < ntiles) bcur[ni] = *(const short8*)(Bb + (size_t)(ni * S1) * 512);
        float4v acc[2][7] = {};
        #pragma unroll 1
        for (int s = 0; s < S1; ++s) {
            if (s < S1 - 1) {
                #pragma unroll
                for (int ni = 0; ni < 7; ++ni)
                    if (ni < ntiles) bnxt[ni] = *(const short8*)(Bb + (size_t)(ni * S1 + s + 1) * 512);
            }
            short8 af[2];
            #pragma unroll
            for (int mt = 0; mt < 2; ++mt)
                af[mt] = *(const short8*)&smA[(mt * 16 + mrow) * SA + s * 32 + quad * 8];
            #pragma unroll
            for (int ni = 0; ni < 7; ++ni)
                if (ni < ntiles)
                    #pragma unroll
                    for (int mt = 0; mt < 2; ++mt)
                        acc[mt][ni] = __builtin_amdgcn_mfma_f32_16x16x32_bf16(af[mt], bcur[ni], acc[mt][ni], 0, 0, 0);
            #pragma unroll
            for (int ni = 0; ni < 7; ++ni) bcur[ni] = bnxt[ni];
        }
        __syncthreads();   // drain smA frag reads before smH overwrites the region
        #pragma unroll
        for (int ni = 0; ni < 7; ++ni)
            if (ni < ntiles) {
                int col = (wv * 7 + ni) * 16 + mrow;     // < 400 by construction
                float bv = b1[col];
                #pragma unroll
                for (int mt = 0; mt < 2; ++mt)
                    #pragma unroll
                    for (int r = 0; r < 4; ++r) {
                        int row = mt * 16 + quad * 4 + r;
                        smH[row * SH + col] = f2bf(fmaxf(acc[mt][ni][r] + bv, 0.f));
                    }
            }
        if (wv == 3) {   // zero pad cols 400..415 (dropped zero-tiles used to write these)
            #pragma unroll
            for (int mt = 0; mt < 2; ++mt)
                #pragma unroll
                for (int r = 0; r < 4; ++r)
                    smH[(mt * 16 + quad * 4 + r) * SH + 400 + mrow] = 0;
        }
    }
    __syncthreads();

    // ---- Phase C: GEMM2 + fused W_out dot ----
    {
        const ushort_t* Bb = W2f + (size_t)(wv * 7 * S2) * 512 + lane * 8;
        short8 bcur[7], bnxt[7];
        #pragma unroll
        for (int ni = 0; ni < 7; ++ni)
            if (ni < ntiles) bcur[ni] = *(const short8*)(Bb + (size_t)(ni * S2) * 512);
        float4v acc[2][7] = {};
        #pragma unroll 1
        for (int s = 0; s < S2; ++s) {
            if (s < S2 - 1) {
                #pragma unroll
                for (int ni = 0; ni < 7; ++ni)
                    if (ni < ntiles) bnxt[ni] = *(const short8*)(Bb + (size_t)(ni * S2 + s + 1) * 512);
            }
            short8 af[2];
            #pragma unroll
            for (int mt = 0; mt < 2; ++mt)
                af[mt] = *(const short8*)&smH[(mt * 16 + mrow) * SH + s * 32 + quad * 8];
            #pragma unroll
            for (int ni = 0; ni < 7; ++ni)
                if (ni < ntiles)
                    #pragma unroll
                    for (int mt = 0; mt < 2; ++mt)
                        acc[mt][ni] = __builtin_amdgcn_mfma_f32_16x16x32_bf16(af[mt], bcur[ni], acc[mt][ni], 0, 0, 0);
            #pragma unroll
            for (int ni = 0; ni < 7; ++ni) bcur[ni] = bnxt[ni];
        }
        float p[2][4] = {};
        #pragma unroll
        for (int ni = 0; ni < 7; ++ni)
            if (ni < ntiles) {
                int col = (wv * 7 + ni) * 16 + mrow;     // < 400
                float bv = b2[col], wvv = Wout[1 + col];
                #pragma unroll
                for (int mt = 0; mt < 2; ++mt)
                    #pragma unroll
                    for (int r = 0; r < 4; ++r)
                        p[mt][r] += fmaxf(acc[mt][ni][r] + bv, 0.f) * wvv;
            }
        #pragma unroll
        for (int mt = 0; mt < 2; ++mt)
            #pragma unroll
            for (int r = 0; r < 4; ++r) {
                float v = p[mt][r];
                v += __shfl_xor(v, 1); v += __shfl_xor(v, 2);
                v += __shfl_xor(v, 4); v += __shfl_xor(v, 8);
                p[mt][r] = v;
            }
        if (mrow == 0) {
            #pragma unroll
            for (int mt = 0; mt < 2; ++mt)
                #pragma unroll
                for (int r = 0; r < 4; ++r)
                    smP[wv * ROWS + mt * 16 + quad * 4 + r] = p[mt][r];
        }
    }
    __syncthreads();

    // ---- finalize: combine 4 wave-partials + FM branch ----
    if (tid < ROWS) {
        float o = smP[tid] + smP[ROWS + tid] + smP[2 * ROWS + tid] + smP[3 * ROWS + tid];
        out[b0 + tid] = o + smFM[tid] * Wout[0] + bout[0];
    }
}

// ================= launch =================
extern "C" void kernel_launch(void* const* d_in, const int* in_sizes, int n_in,
                              void* d_out, int out_size, void* d_ws, size_t ws_size,
                              hipStream_t stream) {
    const float* cont    = (const float*)d_in[0];
    const int*   cat     = (const int*)d_in[1];
    const float* w_cont  = (const float*)d_in[2];
    const float* b_cont  = (const float*)d_in[3];
    const float* t_first = (const float*)d_in[4];
    const float* t_emb   = (const float*)d_in[5];
    const float* W1      = (const float*)d_in[6];
    const float* b1      = (const float*)d_in[7];
    const float* W2      = (const float*)d_in[8];
    const float* b2      = (const float*)d_in[9];
    const float* Wout    = (const float*)d_in[10];
    const float* bout    = (const float*)d_in[11];
    float* out = (float*)d_out;

    char* w = (char*)d_ws;
    ushort_t* W1f = (ushort_t*)(w + OFF_W1F);
    ushort_t* W2f = (ushort_t*)(w + OFF_W2F);

    // K0: weight prep (400*480 + 400*416 = 358400 elems = 1400 * 256)
    prep_weights<<<1400, 256, 0, stream>>>(W1, W2, W1f, W2f);
    // K1: fully fused forward, 2 blocks/CU
    fused_deepfm<<<BATCH / ROWS, 256, 0, stream>>>(cont, cat, w_cont, b_cont,
                                                   t_first, t_emb, W1f, b1, W2f, b2,
                                                   Wout, bout, out);
}

// Round 6
// 260.739 us; speedup vs baseline: 1.1578x; 1.0199x over previous
//
#include <hip/hip_runtime.h>

// ---------------- bf16 helpers (raw ushort storage; RNE convert) ----------------
typedef unsigned short ushort_t;
typedef unsigned int uint_t;

__device__ __forceinline__ float bf2f(ushort_t u) {
    union { float f; uint_t i; } c; c.i = ((uint_t)u) << 16; return c.f;
}
__device__ __forceinline__ ushort_t f2bf(float f) {
    union { float f; uint_t i; } c; c.f = f;
    uint_t i = c.i;
    return (ushort_t)((i + 0x7fffu + ((i >> 16) & 1u)) >> 16);   // RNE
}

typedef __attribute__((ext_vector_type(8))) short short8;
typedef __attribute__((ext_vector_type(4))) float float4v;

// ---------------- problem constants ----------------
#define BATCH 16384
#define NV    100000
#define K1    480     // [0..415] emb | [416..431] c_hi | [432..447] c_lo | [448..463] c_hi | [464..479] 0
#define K2    416     // h1 400 + 16 zero pad
#define S1    15      // K1/32
#define S2    13      // K2/32
#define ROWS  64      // batch rows per block (M-reuse: halves per-row B traffic vs 32)
#define WPB   8       // waves per block (512 thr -> 2 waves/SIMD)
#define SA    488     // smA row stride (elems); 976 B -> row skew -> <=2-way (free)
#define SH    456     // smH row stride; 912 B -> <=2-way (free)

// fragment-ordered weights: frag(t,s) = 64 lanes x 16B contiguous (1 KB)
#define OFF_W1F 0u           // 25*15*512*2 = 384000 B
#define OFF_W2F 384000u      // 25*13*512*2 = 332800 B  (total ~700 KB ws)

// ================= K0: cast + hi/lo split + repack to fragment order =================
__global__ void prep_weights(const float* __restrict__ W1, const float* __restrict__ W2,
                             ushort_t* __restrict__ W1f, ushort_t* __restrict__ W2f) {
    int i = blockIdx.x * 256 + threadIdx.x;
    if (i < 400 * K1) {
        int n = i / K1, k = i % K1;
        ushort_t o = 0;
        if (k < 416) {
            o = f2bf(W1[(size_t)(13 + k) * 400 + n]);            // emb rows
        } else if (k < 448) {
            int j = k - (k < 432 ? 416 : 432);
            if (j < 13) o = f2bf(W1[(size_t)j * 400 + n]);       // w_hi (twice)
        } else if (k < 464) {
            int j = k - 448;
            if (j < 13) {
                float wv = W1[(size_t)j * 400 + n];
                o = f2bf(wv - bf2f(f2bf(wv)));                   // w_lo
            }
        }
        int t = n >> 4, mr = n & 15, s = k >> 5, q = (k >> 3) & 3, j = k & 7;
        W1f[(size_t)((t * S1 + s) * 64 + q * 16 + mr) * 8 + j] = o;
    } else {
        int i2 = i - 400 * K1;
        if (i2 < 400 * K2) {
            int n = i2 / K2, k = i2 % K2;
            ushort_t o = (k < 400) ? f2bf(W2[(size_t)k * 400 + n]) : (ushort_t)0;
            int t = n >> 4, mr = n & 15, s = k >> 5, q = (k >> 3) & 3, j = k & 7;
            W2f[(size_t)((t * S2 + s) * 64 + q * 16 + mr) * 8 + j] = o;
        }
    }
}

// ================= K1: fully fused DeepFM =================
// 256 blocks x 512 threads; block owns 64 batch rows (max M-reuse of the L2-resident
// weight stream); 8 waves = 2/SIMD; ragged N-split {4,3x7} over 25 tiles.
__global__ __launch_bounds__(512, 2) void fused_deepfm(
    const float* __restrict__ cont, const int* __restrict__ cat,
    const float* __restrict__ w_cont, const float* __restrict__ b_cont,
    const float* __restrict__ t_first, const float* __restrict__ t_emb,
    const ushort_t* __restrict__ W1f, const float* __restrict__ b1,
    const ushort_t* __restrict__ W2f, const float* __restrict__ b2,
    const float* __restrict__ Wout, const float* __restrict__ bout,
    float* __restrict__ out)
{
    __shared__ __align__(16) ushort_t smA[ROWS * SA];   // 62464 B; aliased by smH (stride SH)
    __shared__ float smFM[ROWS];                        // 256 B
    __shared__ float smP[WPB * ROWS];                   // 2048 B  (total 64768 <= 64 KB)

    int tid  = threadIdx.x;
    int wv   = tid >> 6, lane = tid & 63;
    int quad = lane >> 4, mrow = lane & 15;
    int b0   = blockIdx.x * ROWS;
    ushort_t* smH = smA;
    const int ntiles = (wv == 0) ? 4 : 3;          // 4+7*3 = 25 real tiles
    const int tbase  = (wv == 0) ? 0 : (1 + 3 * wv);

    // ---- Phase A: gather + FM (fp32 exact) + build dnn tile in LDS ----
    {
        int r4 = lane >> 4, fs = (lane >> 2) & 3, sub = lane & 3, l16 = lane & 15;
        int idxv[2][7];
        #pragma unroll
        for (int g = 0; g < 2; ++g) {
            int gR = b0 + wv * 8 + g * 4 + r4;
            #pragma unroll
            for (int it = 0; it < 7; ++it) {
                int f = it * 4 + fs;
                idxv[g][it] = (f < 26) ? cat[gR * 26 + f] : 0;
            }
        }
        #pragma unroll
        for (int g = 0; g < 2; ++g) {
            int R  = wv * 8 + g * 4 + r4;
            int gR = b0 + R;
            float sj0 = 0, sj1 = 0, sj2 = 0, sj3 = 0, ssq = 0, pacc = 0;
            #pragma unroll
            for (int it = 0; it < 7; ++it) {
                int f = it * 4 + fs;
                if (f < 26) {
                    int idx = idxv[g][it];
                    const float* ep = t_emb + (((size_t)f * NV + idx) << 4) + sub * 4;
                    float4 v = *(const float4*)ep;
                    sj0 += v.x; sj1 += v.y; sj2 += v.z; sj3 += v.w;
                    ssq += v.x * v.x + v.y * v.y + v.z * v.z + v.w * v.w;
                    uint_t lo = (uint_t)f2bf(v.x) | ((uint_t)f2bf(v.y) << 16);
                    uint_t hi = (uint_t)f2bf(v.z) | ((uint_t)f2bf(v.w) << 16);
                    uint2 pk = make_uint2(lo, hi);
                    *(uint2*)&smA[R * SA + f * 16 + sub * 4] = pk;   // 8B-aligned
                    if (sub == 0) pacc += t_first[(size_t)f * NV + idx];
                }
            }
            float c = (l16 < 13) ? cont[gR * 13 + l16] : 0.f;
            if (l16 < 13) pacc += c * w_cont[l16];
            ushort_t ch = f2bf(c);
            float cl = c - bf2f(ch);
            smA[R * SA + 416 + l16] = ch;
            smA[R * SA + 432 + l16] = f2bf(cl);
            smA[R * SA + 448 + l16] = ch;
            smA[R * SA + 464 + l16] = 0;
            sj0 += __shfl_xor(sj0, 4); sj0 += __shfl_xor(sj0, 8);
            sj1 += __shfl_xor(sj1, 4); sj1 += __shfl_xor(sj1, 8);
            sj2 += __shfl_xor(sj2, 4); sj2 += __shfl_xor(sj2, 8);
            sj3 += __shfl_xor(sj3, 4); sj3 += __shfl_xor(sj3, 8);
            float q = pacc - 0.5f * ssq;
            if (fs == 0) q += 0.5f * (sj0 * sj0 + sj1 * sj1 + sj2 * sj2 + sj3 * sj3);
            q += __shfl_xor(q, 1); q += __shfl_xor(q, 2);
            q += __shfl_xor(q, 4); q += __shfl_xor(q, 8);
            if (l16 == 0) smFM[R] = q + b_cont[0];
        }
    }
    __syncthreads();

    // ---- Phase B: GEMM1, fragment-ordered B streamed L2->regs, A from LDS ----
    {
        const ushort_t* Bb = W1f + (size_t)(tbase * S1) * 512 + lane * 8;
        short8 bcur[4], bnxt[4];
        #pragma unroll
        for (int ni = 0; ni < 4; ++ni)
            if (ni < ntiles) bcur[ni] = *(const short8*)(Bb + (size_t)(ni * S1) * 512);
        float4v acc[4][4] = {};
        #pragma unroll 1
        for (int s = 0; s < S1; ++s) {
            if (s < S1 - 1) {
                #pragma unroll
                for (int ni = 0; ni < 4; ++ni)
                    if (ni < ntiles) bnxt[ni] = *(const short8*)(Bb + (size_t)(ni * S1 + s + 1) * 512);
            }
            short8 af[4];
            #pragma unroll
            for (int mt = 0; mt < 4; ++mt)
                af[mt] = *(const short8*)&smA[(mt * 16 + mrow) * SA + s * 32 + quad * 8];
            #pragma unroll
            for (int ni = 0; ni < 4; ++ni)
                if (ni < ntiles)
                    #pragma unroll
                    for (int mt = 0; mt < 4; ++mt)
                        acc[mt][ni] = __builtin_amdgcn_mfma_f32_16x16x32_bf16(af[mt], bcur[ni], acc[mt][ni], 0, 0, 0);
            #pragma unroll
            for (int ni = 0; ni < 4; ++ni) bcur[ni] = bnxt[ni];
        }
        __syncthreads();   // drain smA frag reads before smH overwrites the region
        #pragma unroll
        for (int ni = 0; ni < 4; ++ni)
            if (ni < ntiles) {
                int col = (tbase + ni) * 16 + mrow;     // < 400 by construction
                float bv = b1[col];
                #pragma unroll
                for (int mt = 0; mt < 4; ++mt)
                    #pragma unroll
                    for (int r = 0; r < 4; ++r) {
                        int row = mt * 16 + quad * 4 + r;
                        smH[row * SH + col] = f2bf(fmaxf(acc[mt][ni][r] + bv, 0.f));
                    }
            }
        if (wv == 7) {   // zero pad cols 400..415 across all 64 rows
            #pragma unroll
            for (int r = 0; r < 16; ++r)
                smH[(r * 4 + quad) * SH + 400 + mrow] = 0;
        }
    }
    __syncthreads();

    // ---- Phase C: GEMM2 + fused W_out dot ----
    {
        const ushort_t* Bb = W2f + (size_t)(tbase * S2) * 512 + lane * 8;
        short8 bcur[4], bnxt[4];
        #pragma unroll
        for (int ni = 0; ni < 4; ++ni)
            if (ni < ntiles) bcur[ni] = *(const short8*)(Bb + (size_t)(ni * S2) * 512);
        float4v acc[4][4] = {};
        #pragma unroll 1
        for (int s = 0; s < S2; ++s) {
            if (s < S2 - 1) {
                #pragma unroll
                for (int ni = 0; ni < 4; ++ni)
                    if (ni < ntiles) bnxt[ni] = *(const short8*)(Bb + (size_t)(ni * S2 + s + 1) * 512);
            }
            short8 af[4];
            #pragma unroll
            for (int mt = 0; mt < 4; ++mt)
                af[mt] = *(const short8*)&smH[(mt * 16 + mrow) * SH + s * 32 + quad * 8];
            #pragma unroll
            for (int ni = 0; ni < 4; ++ni)
                if (ni < ntiles)
                    #pragma unroll
                    for (int mt = 0; mt < 4; ++mt)
                        acc[mt][ni] = __builtin_amdgcn_mfma_f32_16x16x32_bf16(af[mt], bcur[ni], acc[mt][ni], 0, 0, 0);
            #pragma unroll
            for (int ni = 0; ni < 4; ++ni) bcur[ni] = bnxt[ni];
        }
        float p[4][4] = {};
        #pragma unroll
        for (int ni = 0; ni < 4; ++ni)
            if (ni < ntiles) {
                int col = (tbase + ni) * 16 + mrow;     // < 400
                float bv = b2[col], wvv = Wout[1 + col];
                #pragma unroll
                for (int mt = 0; mt < 4; ++mt)
                    #pragma unroll
                    for (int r = 0; r < 4; ++r)
                        p[mt][r] += fmaxf(acc[mt][ni][r] + bv, 0.f) * wvv;
            }
        #pragma unroll
        for (int mt = 0; mt < 4; ++mt)
            #pragma unroll
            for (int r = 0; r < 4; ++r) {
                float v = p[mt][r];
                v += __shfl_xor(v, 1); v += __shfl_xor(v, 2);
                v += __shfl_xor(v, 4); v += __shfl_xor(v, 8);
                p[mt][r] = v;
            }
        if (mrow == 0) {
            #pragma unroll
            for (int mt = 0; mt < 4; ++mt)
                #pragma unroll
                for (int r = 0; r < 4; ++r)
                    smP[wv * ROWS + mt * 16 + quad * 4 + r] = p[mt][r];
        }
    }
    __syncthreads();

    // ---- finalize: combine 8 wave-partials + FM branch ----
    if (tid < ROWS) {
        float o = 0.f;
        #pragma unroll
        for (int w = 0; w < WPB; ++w) o += smP[w * ROWS + tid];
        out[b0 + tid] = o + smFM[tid] * Wout[0] + bout[0];
    }
}

// ================= launch =================
extern "C" void kernel_launch(void* const* d_in, const int* in_sizes, int n_in,
                              void* d_out, int out_size, void* d_ws, size_t ws_size,
                              hipStream_t stream) {
    const float* cont    = (const float*)d_in[0];
    const int*   cat     = (const int*)d_in[1];
    const float* w_cont  = (const float*)d_in[2];
    const float* b_cont  = (const float*)d_in[3];
    const float* t_first = (const float*)d_in[4];
    const float* t_emb   = (const float*)d_in[5];
    const float* W1      = (const float*)d_in[6];
    const float* b1      = (const float*)d_in[7];
    const float* W2      = (const float*)d_in[8];
    const float* b2      = (const float*)d_in[9];
    const float* Wout    = (const float*)d_in[10];
    const float* bout    = (const float*)d_in[11];
    float* out = (float*)d_out;

    char* w = (char*)d_ws;
    ushort_t* W1f = (ushort_t*)(w + OFF_W1F);
    ushort_t* W2f = (ushort_t*)(w + OFF_W2F);

    // K0: weight prep (400*480 + 400*416 = 358400 elems = 1400 * 256)
    prep_weights<<<1400, 256, 0, stream>>>(W1, W2, W1f, W2f);
    // K1: fully fused forward, 64 rows/block, 8 waves
    fused_deepfm<<<BATCH / ROWS, 512, 0, stream>>>(cont, cat, w_cont, b_cont,
                                                   t_first, t_emb, W1f, b1, W2f, b2,
                                                   Wout, bout, out);
}

// Round 7
// 259.292 us; speedup vs baseline: 1.1643x; 1.0056x over previous
//
#include <hip/hip_runtime.h>

// ---------------- bf16 helpers (raw ushort storage; RNE convert) ----------------
typedef unsigned short ushort_t;
typedef unsigned int uint_t;

__device__ __forceinline__ float bf2f(ushort_t u) {
    union { float f; uint_t i; } c; c.i = ((uint_t)u) << 16; return c.f;
}
__device__ __forceinline__ ushort_t f2bf(float f) {
    union { float f; uint_t i; } c; c.f = f;
    uint_t i = c.i;
    return (ushort_t)((i + 0x7fffu + ((i >> 16) & 1u)) >> 16);   // RNE
}

typedef __attribute__((ext_vector_type(8))) short short8;
typedef __attribute__((ext_vector_type(4))) float float4v;

// ---------------- problem constants ----------------
#define BATCH 16384
#define NV    100000
#define K1    480     // [0..415] emb | [416..431] c_hi | [432..447] c_lo | [448..463] c_hi | [464..479] 0
#define K2    416     // h1 400 + 16 zero pad
#define S1    15      // K1/32
#define S2    13      // K2/32
#define ROWS  64      // batch rows per block (max M-reuse of L2 weight stream)
#define WPB   8       // waves per block (512 thr -> 2 waves/SIMD)
#define SA    488     // smA row stride (elems); 976 B -> row skew -> <=2-way (free)
#define SH    456     // smH row stride; 912 B -> <=2-way (free)

// fragment-ordered weights: frag(t,s) = 64 lanes x 16B contiguous (1 KB)
#define OFF_W1F 0u           // 25*15*512*2 = 384000 B
#define OFF_W2F 384000u      // 25*13*512*2 = 332800 B  (total ~700 KB ws)

// ================= K0: fragment-parallel weight prep =================
// One 64-lane wave builds one 1 KB fragment: lane writes one coalesced short8;
// the 16 lanes of each n-group share every 64 B read granule of W1/W2.
// 700 frags x 64 lanes = 44800 threads = 175 blocks x 256.
__global__ void prep_weights(const float* __restrict__ W1, const float* __restrict__ W2,
                             ushort_t* __restrict__ W1f, ushort_t* __restrict__ W2f) {
    int gid  = blockIdx.x * 256 + threadIdx.x;
    int frag = gid >> 6, lane = gid & 63;
    int q = lane >> 4, mr = lane & 15;
    short8 o;
    if (frag < 25 * S1) {                       // W1 fragment
        int t = frag / S1, s = frag % S1;
        int n = t * 16 + mr;
        #pragma unroll
        for (int j = 0; j < 8; ++j) {
            int k = s * 32 + q * 8 + j;
            float v = 0.f;
            if (k < 416) {
                v = W1[(size_t)(13 + k) * 400 + n];                  // emb rows
            } else if (k < 448) {
                int j2 = k - (k < 432 ? 416 : 432);
                if (j2 < 13) v = W1[(size_t)j2 * 400 + n];           // w_hi (twice)
            } else if (k < 464) {
                int j2 = k - 448;
                if (j2 < 13) {
                    float wv = W1[(size_t)j2 * 400 + n];
                    v = wv - bf2f(f2bf(wv));                          // w_lo
                }
            }
            o[j] = (short)((k >= 448 && k < 464) ? f2bf(v) : f2bf(v));
        }
        // note: for w_lo rows v already holds the residual; f2bf applied uniformly
        *(short8*)&W1f[(size_t)(frag * 64 + lane) * 8] = o;
    } else if (frag < 25 * (S1 + S2)) {         // W2 fragment
        int f2i = frag - 25 * S1;
        int t = f2i / S2, s = f2i % S2;
        int n = t * 16 + mr;
        #pragma unroll
        for (int j = 0; j < 8; ++j) {
            int k = s * 32 + q * 8 + j;
            float v = (k < 400) ? W2[(size_t)k * 400 + n] : 0.f;
            o[j] = (short)f2bf(v);
        }
        *(short8*)&W2f[(size_t)(f2i * 64 + lane) * 8] = o;
    }
}

// ================= K1: fully fused DeepFM =================
// 256 blocks x 512 threads; block owns 64 batch rows; ragged N-split {4,3x7}.
__global__ __launch_bounds__(512, 2) void fused_deepfm(
    const float* __restrict__ cont, const int* __restrict__ cat,
    const float* __restrict__ w_cont, const float* __restrict__ b_cont,
    const float* __restrict__ t_first, const float* __restrict__ t_emb,
    const ushort_t* __restrict__ W1f, const float* __restrict__ b1,
    const ushort_t* __restrict__ W2f, const float* __restrict__ b2,
    const float* __restrict__ Wout, const float* __restrict__ bout,
    float* __restrict__ out)
{
    __shared__ __align__(16) ushort_t smA[ROWS * SA];   // 62464 B; aliased by smH (stride SH)
    __shared__ float smFM[ROWS];                        // 256 B
    __shared__ float smP[WPB * ROWS];                   // 2048 B  (total 64768 <= 64 KB)

    int tid  = threadIdx.x;
    int wv   = tid >> 6, lane = tid & 63;
    int quad = lane >> 4, mrow = lane & 15;
    int b0   = blockIdx.x * ROWS;
    ushort_t* smH = smA;
    const int ntiles = (wv == 0) ? 4 : 3;          // 4+7*3 = 25 real tiles
    const int tbase  = (wv == 0) ? 0 : (1 + 3 * wv);

    // ---- Phase A: gather + FM (fp32 exact) + build dnn tile in LDS ----
    {
        int r4 = lane >> 4, fs = (lane >> 2) & 3, sub = lane & 3, l16 = lane & 15;
        // hoist ALL loads (indices, 14x emb float4, 14x t_first, 2x cont) for max MLP
        int idxv[2][7];
        #pragma unroll
        for (int g = 0; g < 2; ++g) {
            int gR = b0 + wv * 8 + g * 4 + r4;
            #pragma unroll
            for (int it = 0; it < 7; ++it) {
                int f = it * 4 + fs;
                idxv[g][it] = (f < 26) ? cat[gR * 26 + f] : 0;
            }
        }
        float4 ev[2][7];
        float  tfv[2][7];
        float  cv[2];
        #pragma unroll
        for (int g = 0; g < 2; ++g) {
            int gR = b0 + wv * 8 + g * 4 + r4;
            cv[g] = (l16 < 13) ? cont[gR * 13 + l16] : 0.f;
            #pragma unroll
            for (int it = 0; it < 7; ++it) {
                int f = it * 4 + fs;
                if (f < 26) {
                    size_t base = (size_t)f * NV + idxv[g][it];
                    ev[g][it]  = *(const float4*)(t_emb + (base << 4) + sub * 4);
                    tfv[g][it] = t_first[base];   // same addr across sub lanes -> merged
                }
            }
        }
        #pragma unroll
        for (int g = 0; g < 2; ++g) {
            int R = wv * 8 + g * 4 + r4;
            float sj0 = 0, sj1 = 0, sj2 = 0, sj3 = 0, ssq = 0, pacc = 0;
            #pragma unroll
            for (int it = 0; it < 7; ++it) {
                int f = it * 4 + fs;
                if (f < 26) {
                    float4 v = ev[g][it];
                    sj0 += v.x; sj1 += v.y; sj2 += v.z; sj3 += v.w;
                    ssq += v.x * v.x + v.y * v.y + v.z * v.z + v.w * v.w;
                    uint_t lo = (uint_t)f2bf(v.x) | ((uint_t)f2bf(v.y) << 16);
                    uint_t hi = (uint_t)f2bf(v.z) | ((uint_t)f2bf(v.w) << 16);
                    uint2 pk = make_uint2(lo, hi);
                    *(uint2*)&smA[R * SA + f * 16 + sub * 4] = pk;   // 8B-aligned
                    if (sub == 0) pacc += tfv[g][it];
                }
            }
            float c = cv[g];
            if (l16 < 13) pacc += c * w_cont[l16];
            ushort_t ch = f2bf(c);
            float cl = c - bf2f(ch);
            smA[R * SA + 416 + l16] = ch;
            smA[R * SA + 432 + l16] = f2bf(cl);
            smA[R * SA + 448 + l16] = ch;
            smA[R * SA + 464 + l16] = 0;
            sj0 += __shfl_xor(sj0, 4); sj0 += __shfl_xor(sj0, 8);
            sj1 += __shfl_xor(sj1, 4); sj1 += __shfl_xor(sj1, 8);
            sj2 += __shfl_xor(sj2, 4); sj2 += __shfl_xor(sj2, 8);
            sj3 += __shfl_xor(sj3, 4); sj3 += __shfl_xor(sj3, 8);
            float q = pacc - 0.5f * ssq;
            if (fs == 0) q += 0.5f * (sj0 * sj0 + sj1 * sj1 + sj2 * sj2 + sj3 * sj3);
            q += __shfl_xor(q, 1); q += __shfl_xor(q, 2);
            q += __shfl_xor(q, 4); q += __shfl_xor(q, 8);
            if (l16 == 0) smFM[R] = q + b_cont[0];
        }
    }
    __syncthreads();

    // ---- Phase B: GEMM1, fragment-ordered B streamed L2->regs, A from LDS ----
    {
        const ushort_t* Bb = W1f + (size_t)(tbase * S1) * 512 + lane * 8;
        short8 bcur[4], bnxt[4];
        #pragma unroll
        for (int ni = 0; ni < 4; ++ni)
            if (ni < ntiles) bcur[ni] = *(const short8*)(Bb + (size_t)(ni * S1) * 512);
        float4v acc[4][4] = {};
        #pragma unroll 1
        for (int s = 0; s < S1; ++s) {
            if (s < S1 - 1) {
                #pragma unroll
                for (int ni = 0; ni < 4; ++ni)
                    if (ni < ntiles) bnxt[ni] = *(const short8*)(Bb + (size_t)(ni * S1 + s + 1) * 512);
            }
            short8 af[4];
            #pragma unroll
            for (int mt = 0; mt < 4; ++mt)
                af[mt] = *(const short8*)&smA[(mt * 16 + mrow) * SA + s * 32 + quad * 8];
            #pragma unroll
            for (int ni = 0; ni < 4; ++ni)
                if (ni < ntiles)
                    #pragma unroll
                    for (int mt = 0; mt < 4; ++mt)
                        acc[mt][ni] = __builtin_amdgcn_mfma_f32_16x16x32_bf16(af[mt], bcur[ni], acc[mt][ni], 0, 0, 0);
            #pragma unroll
            for (int ni = 0; ni < 4; ++ni) bcur[ni] = bnxt[ni];
        }
        __syncthreads();   // drain smA frag reads before smH overwrites the region
        #pragma unroll
        for (int ni = 0; ni < 4; ++ni)
            if (ni < ntiles) {
                int col = (tbase + ni) * 16 + mrow;     // < 400 by construction
                float bv = b1[col];
                #pragma unroll
                for (int mt = 0; mt < 4; ++mt)
                    #pragma unroll
                    for (int r = 0; r < 4; ++r) {
                        int row = mt * 16 + quad * 4 + r;
                        smH[row * SH + col] = f2bf(fmaxf(acc[mt][ni][r] + bv, 0.f));
                    }
            }
        if (wv == 7) {   // zero pad cols 400..415 across all 64 rows
            #pragma unroll
            for (int r = 0; r < 16; ++r)
                smH[(r * 4 + quad) * SH + 400 + mrow] = 0;
        }
    }
    __syncthreads();

    // ---- Phase C: GEMM2 + fused W_out dot ----
    {
        const ushort_t* Bb = W2f + (size_t)(tbase * S2) * 512 + lane * 8;
        short8 bcur[4], bnxt[4];
        #pragma unroll
        for (int ni = 0; ni < 4; ++ni)
            if (ni < ntiles) bcur[ni] = *(const short8*)(Bb + (size_t)(ni * S2) * 512);
        float4v acc[4][4] = {};
        #pragma unroll 1
        for (int s = 0; s < S2; ++s) {
            if (s < S2 - 1) {
                #pragma unroll
                for (int ni = 0; ni < 4; ++ni)
                    if (ni < ntiles) bnxt[ni] = *(const short8*)(Bb + (size_t)(ni * S2 + s + 1) * 512);
            }
            short8 af[4];
            #pragma unroll
            for (int mt = 0; mt < 4; ++mt)
                af[mt] = *(const short8*)&smH[(mt * 16 + mrow) * SH + s * 32 + quad * 8];
            #pragma unroll
            for (int ni = 0; ni < 4; ++ni)
                if (ni < ntiles)
                    #pragma unroll
                    for (int mt = 0; mt < 4; ++mt)
                        acc[mt][ni] = __builtin_amdgcn_mfma_f32_16x16x32_bf16(af[mt], bcur[ni], acc[mt][ni], 0, 0, 0);
            #pragma unroll
            for (int ni = 0; ni < 4; ++ni) bcur[ni] = bnxt[ni];
        }
        float p[4][4] = {};
        #pragma unroll
        for (int ni = 0; ni < 4; ++ni)
            if (ni < ntiles) {
                int col = (tbase + ni) * 16 + mrow;     // < 400
                float bv = b2[col], wvv = Wout[1 + col];
                #pragma unroll
                for (int mt = 0; mt < 4; ++mt)
                    #pragma unroll
                    for (int r = 0; r < 4; ++r)
                        p[mt][r] += fmaxf(acc[mt][ni][r] + bv, 0.f) * wvv;
            }
        #pragma unroll
        for (int mt = 0; mt < 4; ++mt)
            #pragma unroll
            for (int r = 0; r < 4; ++r) {
                float v = p[mt][r];
                v += __shfl_xor(v, 1); v += __shfl_xor(v, 2);
                v += __shfl_xor(v, 4); v += __shfl_xor(v, 8);
                p[mt][r] = v;
            }
        if (mrow == 0) {
            #pragma unroll
            for (int mt = 0; mt < 4; ++mt)
                #pragma unroll
                for (int r = 0; r < 4; ++r)
                    smP[wv * ROWS + mt * 16 + quad * 4 + r] = p[mt][r];
        }
    }
    __syncthreads();

    // ---- finalize: combine 8 wave-partials + FM branch ----
    if (tid < ROWS) {
        float o = 0.f;
        #pragma unroll
        for (int w = 0; w < WPB; ++w) o += smP[w * ROWS + tid];
        out[b0 + tid] = o + smFM[tid] * Wout[0] + bout[0];
    }
}

// ================= launch =================
extern "C" void kernel_launch(void* const* d_in, const int* in_sizes, int n_in,
                              void* d_out, int out_size, void* d_ws, size_t ws_size,
                              hipStream_t stream) {
    const float* cont    = (const float*)d_in[0];
    const int*   cat     = (const int*)d_in[1];
    const float* w_cont  = (const float*)d_in[2];
    const float* b_cont  = (const float*)d_in[3];
    const float* t_first = (const float*)d_in[4];
    const float* t_emb   = (const float*)d_in[5];
    const float* W1      = (const float*)d_in[6];
    const float* b1      = (const float*)d_in[7];
    const float* W2      = (const float*)d_in[8];
    const float* b2      = (const float*)d_in[9];
    const float* Wout    = (const float*)d_in[10];
    const float* bout    = (const float*)d_in[11];
    float* out = (float*)d_out;

    char* w = (char*)d_ws;
    ushort_t* W1f = (ushort_t*)(w + OFF_W1F);
    ushort_t* W2f = (ushort_t*)(w + OFF_W2F);

    // K0: fragment-parallel weight prep (700 frags x 64 lanes = 175 blocks)
    prep_weights<<<175, 256, 0, stream>>>(W1, W2, W1f, W2f);
    // K1: fully fused forward, 64 rows/block, 8 waves
    fused_deepfm<<<BATCH / ROWS, 512, 0, stream>>>(cont, cat, w_cont, b_cont,
                                                   t_first, t_emb, W1f, b1, W2f, b2,
                                                   Wout, bout, out);
}